// Round 7
// baseline (77910.175 us; speedup 1.0000x reference)
//
#include <hip/hip_runtime.h>
#include <hip/hip_bf16.h>

// LSTM (2-layer, T=1024) + STE binarize + FC, MI355X.
// Round 7 = Round 6 + (a) non-temporal 'nt' on bypass h loads and x loads so
// the A-stream stops evicting the per-XCD L2 weight slice (R6's FETCH_SIZE
// showed B refetch), (b) lookahead-2 3-stage counted pipeline (VMW(24)).

typedef _Float16 f16;
typedef __attribute__((ext_vector_type(8))) _Float16 f16x8;
typedef __attribute__((ext_vector_type(4))) float f32x4;

#define MFMA(a, b, c) __builtin_amdgcn_mfma_f32_16x16x32_f16((a), (b), (c), 0, 0, 0)
#define H8(v) __builtin_bit_cast(f16x8, v)

// MALL-coherent bypass load, non-temporal (h state)
#define GLB(dst, ptr) asm volatile("global_load_dwordx4 %0, %1, off sc0 sc1 nt" : "=v"(dst) : "v"(ptr) : "memory")
// streaming cached load, non-temporal (x)
#define GLX(dst, ptr) asm volatile("global_load_dwordx4 %0, %1, off nt" : "=v"(dst) : "v"(ptr) : "memory")
// cached load (weights: L2-resident)
#define GLC(dst, ptr) asm volatile("global_load_dwordx4 %0, %1, off" : "=v"(dst) : "v"(ptr) : "memory")
#define VMW(n) do { asm volatile("s_waitcnt vmcnt(" #n ")" ::: "memory"); __builtin_amdgcn_sched_barrier(0); } while (0)

#define NB 512
#define NT 1024
#define NF 128
#define NH 512
#define NGC 2048
#define K0 640       // NH + NF
#define K1 1024      // 2*NH
#define NBLK 256
#define NTHR 512
#define MB 1048576   // bytes per packed h buffer (512*512*4B)
// packed h cell layout: [rowblk(32)][kblk(16)][lane(64)][hi 16B | lo 16B]
#define RBS 32768    // rowblk stride bytes
#define KBS 2048     // kblk stride bytes
// weight byte strides
#define GS0 655360   // gate stride W0 (NH*K0*2)
#define CS0 20480    // 16-col stride W0
#define GS1 1048576  // gate stride W1 (NH*K1*2)
#define CS1 32768    // 16-col stride W1
#define XR  8388608  // x row-block stride (16*NT*NF*4)
#define GETREG_XCC 63508  // hwreg(HW_REG_XCC_ID=20,0,32)

__device__ __forceinline__ float sigf(float v) { return 1.0f / (1.0f + expf(-v)); }

// coherent 4B (f16x2) write-through store
__device__ __forceinline__ void cstore2(void* p, f16 a, f16 b) {
    union { f16 h[2]; unsigned u; } x;
    x.h[0] = a; x.h[1] = b;
    __hip_atomic_store((unsigned*)p, x.u, __ATOMIC_RELAXED, __HIP_MEMORY_SCOPE_AGENT);
}

__device__ __forceinline__ void splitr(f32x4 u0, f32x4 u1, f16x8& hi, f16x8& lo) {
#pragma unroll
    for (int e = 0; e < 4; ++e) {
        float v = u0[e];
        f16 h = (f16)v;
        hi[e] = h;
        lo[e] = (f16)(v - (float)h);
    }
#pragma unroll
    for (int e = 0; e < 4; ++e) {
        float v = u1[e];
        f16 h = (f16)v;
        hi[4 + e] = h;
        lo[4 + e] = (f16)(v - (float)h);
    }
}

// ---------------- prep: split weights into packed hi/lo f16, sum biases ----------------
__global__ __launch_bounds__(256) void prep_kernel(
    const float* __restrict__ Wih0, const float* __restrict__ Whh0,
    const float* __restrict__ bih0, const float* __restrict__ bhh0,
    const float* __restrict__ Wih1, const float* __restrict__ Whh1,
    const float* __restrict__ bih1, const float* __restrict__ bhh1,
    f16* __restrict__ W0h, f16* __restrict__ W0l,
    f16* __restrict__ W1h, f16* __restrict__ W1l,
    float* __restrict__ bias0, float* __restrict__ bias1)
{
    const int stride = gridDim.x * blockDim.x;
    const int idx = blockIdx.x * blockDim.x + threadIdx.x;
    const int total0 = NGC * K0;
    for (int i = idx; i < total0; i += stride) {
        int gc = i / K0, k = i - gc * K0;
        float w = (k < NH) ? Whh0[gc * NH + k] : Wih0[gc * NF + (k - NH)];
        f16 h = (f16)w;
        W0h[i] = h;
        W0l[i] = (f16)(w - (float)h);
    }
    const int total1 = NGC * K1;
    for (int i = idx; i < total1; i += stride) {
        int gc = i / K1, k = i - gc * K1;
        float w = (k < NH) ? Wih1[gc * NH + k] : Whh1[gc * NH + (k - NH)];
        f16 h = (f16)w;
        W1h[i] = h;
        W1l[i] = (f16)(w - (float)h);
    }
    for (int i = idx; i < NGC; i += stride) {
        bias0[i] = bih0[i] + bhh0[i];
        bias1[i] = bih1[i] + bhh1[i];
    }
}

// A k-step into stage st: 2 rowblocks x (hi,lo) = 4 bypass nt loads
#define ISSA(st, aB, ko) do { \
    GLB(Ast[st][0], (aB) + (ko));       GLB(Ast[st][1], (aB) + (ko) + 16); \
    GLB(Ast[st][2], (aB) + (ko) + RBS); GLB(Ast[st][3], (aB) + (ko) + RBS + 16); \
} while (0)

// B k-step into stage st: 2 gates x 2 col-halves x (hi,lo) = 8 cached loads
#define ISSB(st, bh_, bl_, GS, CS, ko) do { \
    GLC(Bst[st][0], (bh_) + (ko));               GLC(Bst[st][1], (bl_) + (ko)); \
    GLC(Bst[st][2], (bh_) + (CS) + (ko));        GLC(Bst[st][3], (bl_) + (CS) + (ko)); \
    GLC(Bst[st][4], (bh_) + (GS) + (ko));        GLC(Bst[st][5], (bl_) + (GS) + (ko)); \
    GLC(Bst[st][6], (bh_) + (GS) + (CS) + (ko)); GLC(Bst[st][7], (bl_) + (GS) + (CS) + (ko)); \
} while (0)

// 24 MFMAs on stage st
#define STEPK(st) do { \
    _Pragma("unroll") for (int cf = 0; cf < 4; ++cf) \
    _Pragma("unroll") for (int rf = 0; rf < 2; ++rf) { \
        acc[cf][rf] = MFMA(H8(Ast[st][rf * 2]),     H8(Bst[st][cf * 2]),     acc[cf][rf]); \
        acc[cf][rf] = MFMA(H8(Ast[st][rf * 2]),     H8(Bst[st][cf * 2 + 1]), acc[cf][rf]); \
        acc[cf][rf] = MFMA(H8(Ast[st][rf * 2 + 1]), H8(Bst[st][cf * 2]),     acc[cf][rf]); \
    } } while (0)

// x step: A from split registers, B in stage 2
#define STEPX() do { \
    _Pragma("unroll") for (int cf = 0; cf < 4; ++cf) \
    _Pragma("unroll") for (int rf = 0; rf < 2; ++rf) { \
        acc[cf][rf] = MFMA(XAh[rf], H8(Bst[2][cf * 2]),     acc[cf][rf]); \
        acc[cf][rf] = MFMA(XAh[rf], H8(Bst[2][cf * 2 + 1]), acc[cf][rf]); \
        acc[cf][rf] = MFMA(XAl[rf], H8(Bst[2][cf * 2]),     acc[cf][rf]); \
    } } while (0)

#define ZACC() do { f32x4 _z = {0.f, 0.f, 0.f, 0.f}; \
    _Pragma("unroll") for (int cf = 0; cf < 4; ++cf) { acc[cf][0] = _z; acc[cf][1] = _z; } } while (0)

#define DUMP() do { \
    _Pragma("unroll") for (int cf = 0; cf < 4; ++cf) \
    _Pragma("unroll") for (int rf = 0; rf < 2; ++rf) \
    _Pragma("unroll") for (int rg = 0; rg < 4; ++rg) \
        ldsG[kq][g0 + (cf >> 1)][rf * 16 + kg * 4 + rg][(cf & 1) * 16 + lm] = acc[cf][rf][rg]; \
} while (0)

// ---------------- main persistent LSTM kernel ----------------
__global__ __launch_bounds__(NTHR, 2) void lstm_kernel(
    const float* __restrict__ x,
    const f16* __restrict__ W0h, const f16* __restrict__ W0l,
    const f16* __restrict__ W1h, const f16* __restrict__ W1l,
    const float* __restrict__ bias0, const float* __restrict__ bias1,
    char* hbB, unsigned* sync,
    float* __restrict__ h1f)
{
    const int tid = threadIdx.x;
    const int lane = tid & 63;
    const int wv = tid >> 6;     // 0..7
    const int gp = wv & 1;       // gate pair: 0={i,f} 1={g,o}
    const int kq = wv >> 1;      // K-quarter 0..3
    const int kg = lane >> 4;
    const int lm = lane & 15;

    __shared__ float ldsG[4][4][32][36]; // [kq][gate][row][col32+pad] partials (73728 B)
    __shared__ char ldsPad[12288];       // force 1 block/CU
    __shared__ int sSlot;

    // ---- real-XCD placement: getreg + slot claim ----
    const unsigned xcd = (unsigned)__builtin_amdgcn_s_getreg(GETREG_XCC) & 7u;
    unsigned* gbar    = sync;
    unsigned* slotCtr = sync + 128 + xcd * 64;
    if (tid == 0) sSlot = (int)__hip_atomic_fetch_add(slotCtr, 1u, __ATOMIC_RELAXED, __HIP_MEMORY_SCOPE_AGENT);
    __syncthreads();
    const int slot = sSlot & 31;
    if (slot < 0) ldsPad[0] = (char)tid; // keep pad alive (never true)
    const int rowTile = slot >> 1;                 // 0..15 (32 rows)
    const int colTile = (int)xcd * 2 + (slot & 1); // 0..15 (32 h-cols)
    const int row0 = rowTile * 32;
    const int rb0 = rowTile * 2;

    const int g0 = gp * 2;
    const int gcb = g0 * NH + colTile * 32 + lm;

    // B base pointers (bytes)
    const char* b0h = (const char*)W0h + ((size_t)gcb * K0 + kq * 128 + kg * 8) * 2;
    const char* b0l = (const char*)W0l + ((size_t)gcb * K0 + kq * 128 + kg * 8) * 2;
    const char* b1h = (const char*)W1h + ((size_t)gcb * K1 + kq * 256 + kg * 8) * 2;
    const char* b1l = (const char*)W1l + ((size_t)gcb * K1 + kq * 256 + kg * 8) * 2;
    const char* xbh = (const char*)W0h + ((size_t)gcb * K0 + NH + kq * 32 + kg * 8) * 2;
    const char* xbl = (const char*)W0l + ((size_t)gcb * K0 + NH + kq * 32 + kg * 8) * 2;

    // x A pointer (row0+lm), advances 512 B per phase
    const char* pxa = (const char*)x + ((size_t)(row0 + lm) * NT * NF + kq * 32 + kg * 8) * 4;

    // A byte offsets within packed h buffers
    const size_t aoff0 = (size_t)rb0 * RBS + (size_t)kq * 4 * KBS + (size_t)lane * 32;
    const size_t aoff1 = (size_t)rb0 * RBS + (size_t)(kq & 1) * 8 * KBS + (size_t)lane * 32;

    // epilogue mapping
    const int er = tid >> 4;
    const int ec = (tid & 15) * 2;
    const int r = row0 + er;
    const size_t sbyte = (size_t)(r >> 4) * RBS + (size_t)colTile * KBS
                       + (size_t)(((ec >> 3) & 3) * 16 + (r & 15)) * 32 + (ec & 7) * 2;
    const int ecol = colTile * 32 + ec;
    float bE[2][4][2];
#pragma unroll
    for (int g = 0; g < 4; ++g)
#pragma unroll
        for (int e = 0; e < 2; ++e) {
            bE[0][g][e] = bias0[g * NH + ecol + e];
            bE[1][g][e] = bias1[g * NH + ecol + e];
        }

    float c0[2] = {0.f, 0.f}, c1[2] = {0.f, 0.f};
    f32x4 acc[4][2];
    f32x4 Ast[3][4];
    f32x4 Bst[3][8];
    f16x8 XAh[2], XAl[2];

    for (int p = 0; p <= NT; ++p) {
        const int pb_ = (p - 1) & 1;
        const int cb_ = p & 1;
        const size_t xoff = (size_t)p * 512;

        // ================= L0 GEMM: x step + 4 h0-steps, lookahead-2 =================
        if (p < NT) {
            ZACC();
            const char* a0B = hbB + (size_t)pb_ * MB + aoff0;
            // xa into Ast[2] (free until step2 issue)
            GLX(Ast[2][0], pxa + xoff);      GLX(Ast[2][1], pxa + xoff + 16);
            GLX(Ast[2][2], pxa + xoff + XR); GLX(Ast[2][3], pxa + xoff + XR + 16);
            ISSB(2, xbh, xbl, GS0, CS0, 0);
            ISSA(0, a0B, 0);    ISSB(0, b0h, b0l, GS0, CS0, 0);
            ISSA(1, a0B, 2048); ISSB(1, b0h, b0l, GS0, CS0, 64);
            VMW(24); // xa + XB done
            splitr(Ast[2][0], Ast[2][1], XAh[0], XAl[0]);
            splitr(Ast[2][2], Ast[2][3], XAh[1], XAl[1]);
            STEPX();
            ISSA(2, a0B, 4096); ISSB(2, b0h, b0l, GS0, CS0, 128);
            VMW(24); STEPK(0);
            ISSA(0, a0B, 6144); ISSB(0, b0h, b0l, GS0, CS0, 192);
            VMW(24); STEPK(1);
            VMW(12); STEPK(2);
            VMW(0);  STEPK(0);
            DUMP();
        }
        __syncthreads();
        // ---- cell L0 ----
        if (p < NT) {
            float gs[4][2];
#pragma unroll
            for (int g = 0; g < 4; ++g) { gs[g][0] = bE[0][g][0]; gs[g][1] = bE[0][g][1]; }
#pragma unroll
            for (int q = 0; q < 4; ++q)
#pragma unroll
                for (int g = 0; g < 4; ++g) {
                    float2 v = *(const float2*)&ldsG[q][g][er][ec];
                    gs[g][0] += v.x; gs[g][1] += v.y;
                }
            f16 hh[2], hl[2];
#pragma unroll
            for (int e = 0; e < 2; ++e) {
                const float cn = sigf(gs[1][e]) * c0[e] + sigf(gs[0][e]) * tanhf(gs[2][e]);
                c0[e] = cn;
                const float h = sigf(gs[3][e]) * tanhf(cn);
                hh[e] = (f16)h;
                hl[e] = (f16)(h - (float)hh[e]);
            }
            char* d = hbB + (size_t)cb_ * MB + sbyte;
            cstore2(d, hh[0], hh[1]);
            cstore2(d + 16, hl[0], hl[1]);
        }
        __syncthreads();
        // ================= L1 GEMM: 8 steps, lookahead-2 =================
        if (p >= 1) {
            ZACC();
            const char* a1B = hbB + (size_t)(kq < 2 ? pb_ : 2 + cb_) * MB + aoff1;
            ISSA(0, a1B, 0);     ISSB(0, b1h, b1l, GS1, CS1, 0);
            ISSA(1, a1B, 2048);  ISSB(1, b1h, b1l, GS1, CS1, 64);
            ISSA(2, a1B, 4096);  ISSB(2, b1h, b1l, GS1, CS1, 128);
            VMW(24); STEPK(0);
            ISSA(0, a1B, 6144);  ISSB(0, b1h, b1l, GS1, CS1, 192);
            VMW(24); STEPK(1);
            ISSA(1, a1B, 8192);  ISSB(1, b1h, b1l, GS1, CS1, 256);
            VMW(24); STEPK(2);
            ISSA(2, a1B, 10240); ISSB(2, b1h, b1l, GS1, CS1, 320);
            VMW(24); STEPK(0);
            ISSA(0, a1B, 12288); ISSB(0, b1h, b1l, GS1, CS1, 384);
            VMW(24); STEPK(1);
            ISSA(1, a1B, 14336); ISSB(1, b1h, b1l, GS1, CS1, 448);
            VMW(24); STEPK(2);
            VMW(12); STEPK(0);
            VMW(0);  STEPK(1);
            DUMP();
        }
        __syncthreads();
        // ---- cell L1 ----
        if (p >= 1) {
            float gs[4][2];
#pragma unroll
            for (int g = 0; g < 4; ++g) { gs[g][0] = bE[1][g][0]; gs[g][1] = bE[1][g][1]; }
#pragma unroll
            for (int q = 0; q < 4; ++q)
#pragma unroll
                for (int g = 0; g < 4; ++g) {
                    float2 v = *(const float2*)&ldsG[q][g][er][ec];
                    gs[g][0] += v.x; gs[g][1] += v.y;
                }
            f16 hh[2], hl[2];
            float hv[2];
#pragma unroll
            for (int e = 0; e < 2; ++e) {
                const float cn = sigf(gs[1][e]) * c1[e] + sigf(gs[0][e]) * tanhf(gs[2][e]);
                c1[e] = cn;
                const float h = sigf(gs[3][e]) * tanhf(cn);
                hv[e] = h;
                hh[e] = (f16)h;
                hl[e] = (f16)(h - (float)hh[e]);
            }
            char* d = hbB + (size_t)(2 + pb_) * MB + sbyte;
            cstore2(d, hh[0], hh[1]);
            cstore2(d + 16, hl[0], hl[1]);
            if (p == NT) {
                const size_t off = (size_t)r * NH + ecol;
                h1f[off] = hv[0];
                h1f[off + 1] = hv[1];
            }
        }
        // ================= grid barrier =================
        if (p < NT) {
            __syncthreads(); // drains vmcnt: h stores visible at coherent point
            if (tid == 0) {
                __hip_atomic_fetch_add(gbar, 1u, __ATOMIC_RELAXED, __HIP_MEMORY_SCOPE_AGENT);
                const unsigned tgt = (unsigned)(p + 1) * NBLK;
                while (__hip_atomic_load(gbar, __ATOMIC_RELAXED, __HIP_MEMORY_SCOPE_AGENT) < tgt) {
                    __builtin_amdgcn_s_sleep(1);
                }
            }
            __syncthreads();
            asm volatile("" ::: "memory");
        }
    }
}

// ---------------- binarize + FC ----------------
__global__ __launch_bounds__(256) void fc_kernel(
    const float* __restrict__ h1f, const float* __restrict__ Wfc,
    const float* __restrict__ bfc, float* __restrict__ out)
{
    const int t = blockIdx.x * blockDim.x + threadIdx.x;
    const int b = t >> 5;
    const int o = t & 31;
    const float4* hr = (const float4*)(h1f + (size_t)b * NH);
    const float4* wr = (const float4*)(Wfc + (size_t)o * NH);
    float s = 0.f;
#pragma unroll 4
    for (int j = 0; j < NH / 4; ++j) {
        float4 h4 = hr[j];
        float4 w4 = wr[j];
        s += (h4.x > 0.f ? w4.x : 0.f) + (h4.y > 0.f ? w4.y : 0.f)
           + (h4.z > 0.f ? w4.z : 0.f) + (h4.w > 0.f ? w4.w : 0.f);
    }
    out[t] = s + bfc[o];
}

extern "C" void kernel_launch(void* const* d_in, const int* in_sizes, int n_in,
                              void* d_out, int out_size, void* d_ws, size_t ws_size,
                              hipStream_t stream) {
    const float* x    = (const float*)d_in[0];
    const float* Wih0 = (const float*)d_in[1];
    const float* Whh0 = (const float*)d_in[2];
    const float* bih0 = (const float*)d_in[3];
    const float* bhh0 = (const float*)d_in[4];
    const float* Wih1 = (const float*)d_in[5];
    const float* Whh1 = (const float*)d_in[6];
    const float* bih1 = (const float*)d_in[7];
    const float* bhh1 = (const float*)d_in[8];
    const float* Wfc  = (const float*)d_in[9];
    const float* bfc  = (const float*)d_in[10];
    float* out = (float*)d_out;
    (void)in_sizes; (void)n_in; (void)out_size; (void)ws_size;

    // workspace layout (~19 MB)
    char* w = (char*)d_ws;
    unsigned* sync = (unsigned*)w;                 // 8 KB sync region
    char* hb = w + 8192;                           // 4 x 1 MB packed h buffers
    char* after_hb = hb + (size_t)4 * MB;
    float* h1f = (float*)after_hb;                 // 1 MB
    float* bias0 = (float*)(after_hb + (size_t)NB * NH * 4);
    float* bias1 = bias0 + NGC;
    f16* W0h = (f16*)(bias1 + NGC);
    f16* W0l = W0h + (size_t)NGC * K0;
    f16* W1h = W0l + (size_t)NGC * K0;
    f16* W1l = W1h + (size_t)NGC * K1;

    // zero sync counters + h buffers (h(-1)=0); replayed each graph launch
    hipMemsetAsync(d_ws, 0, 8192 + (size_t)4 * MB, stream);

    prep_kernel<<<2048, 256, 0, stream>>>(Wih0, Whh0, bih0, bhh0, Wih1, Whh1, bih1, bhh1,
                                          W0h, W0l, W1h, W1l, bias0, bias1);

    lstm_kernel<<<NBLK, NTHR, 0, stream>>>(x, W0h, W0l, W1h, W1l, bias0, bias1,
                                           hb, sync, h1f);

    fc_kernel<<<64, 256, 0, stream>>>(h1f, Wfc, bfc, out);
}

// Round 8
// 38488.779 us; speedup vs baseline: 2.0242x; 2.0242x over previous
//
#include <hip/hip_runtime.h>
#include <hip/hip_bf16.h>

// LSTM (2-layer, T=1024) + STE binarize + FC, MI355X.
// Round 8: full LDS-DMA streaming rewrite. Unified 52-step K-loop per phase;
// both A (h-state, coherent aux=SC0|SC1) and B (weights, L2-pinned via real-XCD
// claim) staged via global_load_lds into 4 double... quad-buffered 20KB slots,
// lookahead-3, per-step counted vmcnt + raw s_barrier (m201 pattern).
// Waves own gate x col-half full-K (no k-reduction); cell via 17KB gate tile.

typedef _Float16 f16;
typedef __attribute__((ext_vector_type(8))) _Float16 f16x8;
typedef __attribute__((ext_vector_type(4))) float f32x4;

#define MFMA(a, b, c) __builtin_amdgcn_mfma_f32_16x16x32_f16((a), (b), (c), 0, 0, 0)

typedef const void gvoid;
typedef void lvoid;
#define GLDS0(g, l)  __builtin_amdgcn_global_load_lds((const __attribute__((address_space(1))) unsigned*)(g), (__attribute__((address_space(3))) unsigned*)(l), 16, 0, 0)
#define GLDS17(g, l) __builtin_amdgcn_global_load_lds((const __attribute__((address_space(1))) unsigned*)(g), (__attribute__((address_space(3))) unsigned*)(l), 16, 0, 17)

#define VMW(n) do { asm volatile("s_waitcnt vmcnt(" #n ")" ::: "memory"); __builtin_amdgcn_sched_barrier(0); } while (0)
#define BAR() do { __builtin_amdgcn_s_barrier(); __builtin_amdgcn_sched_barrier(0); } while (0)
#define LGKM0() do { asm volatile("s_waitcnt lgkmcnt(0)" ::: "memory"); __builtin_amdgcn_sched_barrier(0); } while (0)

#define NB 512
#define NT 1024
#define NH 512
#define NF 128
#define NGC 2048
#define NBLK 256
#define NTHR 512
#define MBUF 1048576  // bytes per h buffer (hi plane 512K + lo plane 512K)
#define PL 524288     // plane stride
#define SLOT 20480    // LDS slot: A 4KB + B 16KB
#define NSTEP 52
#define WCT 851968    // Wpk bytes per colTile (52 steps * 16384)
#define GETREG_XCC 63508

__device__ __forceinline__ float sigf(float v) { return 1.0f / (1.0f + expf(-v)); }

__device__ __forceinline__ void cstore2(void* p, f16 a, f16 b) {
    union { f16 h[2]; unsigned u; } x;
    x.h[0] = a; x.h[1] = b;
    __hip_atomic_store((unsigned*)p, x.u, __ATOMIC_RELAXED, __HIP_MEMORY_SCOPE_AGENT);
}

__device__ __forceinline__ void splitr(f32x4 u0, f32x4 u1, f16x8& hi, f16x8& lo) {
#pragma unroll
    for (int e = 0; e < 4; ++e) {
        float v = u0[e];
        f16 h = (f16)v;
        hi[e] = h;
        lo[e] = (f16)(v - (float)h);
    }
#pragma unroll
    for (int e = 0; e < 4; ++e) {
        float v = u1[e];
        f16 h = (f16)v;
        hi[4 + e] = h;
        lo[4 + e] = (f16)(v - (float)h);
    }
}

// ---------------- prep: build DMA-native packed weights + biases ----------------
// Wpk layout: [ct 16][step 52][wave 8][plane 2][lane 64][elem 8] f16
// step: 0-15 Whh0(k=s*32..), 16-19 Wih0, 20-35 Wih1(h0 input), 36-51 Whh1
// wave w: gate = w>>1, colhalf = w&1; lane l: gcol_local = ch*16 + (l&15),
// k = kbase + (l>>4)*8 + e.
__global__ __launch_bounds__(256) void prep_kernel(
    const float* __restrict__ Wih0, const float* __restrict__ Whh0,
    const float* __restrict__ bih0, const float* __restrict__ bhh0,
    const float* __restrict__ Wih1, const float* __restrict__ Whh1,
    const float* __restrict__ bih1, const float* __restrict__ bhh1,
    f16* __restrict__ Wpk, float* __restrict__ bias0, float* __restrict__ bias1)
{
    const int stride = gridDim.x * blockDim.x;
    const int idx = blockIdx.x * blockDim.x + threadIdx.x;
    const int total = 16 * 52 * 8 * 2 * 64 * 8; // 6815744
    for (int i = idx; i < total; i += stride) {
        const int e = i & 7;
        const int l = (i >> 3) & 63;
        const int pl = (i >> 9) & 1;
        const int w = (i >> 10) & 7;
        const int rest = i >> 13;
        const int s = rest % 52;
        const int ct = rest / 52;
        const int g = w >> 1, ch = w & 1;
        const int gcol = g * 512 + ct * 32 + ch * 16 + (l & 15);
        const int kk = (l >> 4) * 8 + e;
        float v;
        if (s < 16)      v = Whh0[gcol * 512 + s * 32 + kk];
        else if (s < 20) v = Wih0[gcol * 128 + (s - 16) * 32 + kk];
        else if (s < 36) v = Wih1[gcol * 512 + (s - 20) * 32 + kk];
        else             v = Whh1[gcol * 512 + (s - 36) * 32 + kk];
        const f16 hi = (f16)v;
        Wpk[i] = pl ? (f16)(v - (float)hi) : hi;
    }
    for (int i = idx; i < NGC; i += stride) {
        bias0[i] = bih0[i] + bhh0[i];
        bias1[i] = bih1[i] + bhh1[i];
    }
}

// ---------------- main persistent LSTM kernel ----------------
__global__ __launch_bounds__(NTHR, 2) void lstm_kernel(
    const float* __restrict__ x,
    const f16* __restrict__ Wpk,
    const float* __restrict__ bias0, const float* __restrict__ bias1,
    char* hbB, unsigned* sync,
    float* __restrict__ h1f)
{
    const int tid = threadIdx.x;
    const int lane = tid & 63;
    const int wv = tid >> 6;   // 0..7: gate = wv>>1, colhalf = wv&1
    const int kg = lane >> 4;
    const int lm = lane & 15;

    __shared__ char ldsRaw[99328] __attribute__((aligned(16))); // 4*20480 slots + 17408 ldsC
    __shared__ int sSlot;
    float* ldsC = (float*)(ldsRaw + 81920); // [4 gates][32 rows][34] floats

    // ---- real-XCD placement: getreg + slot claim (1 block/CU via 97KB LDS) ----
    const unsigned xcd = (unsigned)__builtin_amdgcn_s_getreg(GETREG_XCC) & 7u;
    unsigned* gbar    = sync;
    unsigned* slotCtr = sync + 128 + xcd * 64;
    if (tid == 0) sSlot = (int)__hip_atomic_fetch_add(slotCtr, 1u, __ATOMIC_RELAXED, __HIP_MEMORY_SCOPE_AGENT);
    __syncthreads();
    const int slot = sSlot & 31;
    const int rowTile = slot >> 1;                 // 0..15 (32 rows)
    const int colTile = (int)xcd * 2 + (slot & 1); // 0..15 (32 h-cols)
    const int row0 = rowTile * 32;
    const int rb0 = rowTile * 2;

    const char* wpkCT = (const char*)Wpk + (size_t)colTile * WCT;
    // x per-thread base: row (row0+lm), feature kg*8, advances 512B per phase
    const char* xBase = (const char*)x + (size_t)(row0 + lm) * 524288 + kg * 32;

    // epilogue mapping: er 0..31 rows, ec col pair
    const int er = tid >> 4;
    const int ec = (tid & 15) * 2;
    const int ecol = colTile * 32 + ec;
    const int r = row0 + er;
    const size_t sbyteP = (size_t)(r >> 4) * 16384 + (size_t)colTile * 1024
                        + (size_t)((ec >> 3) * 16 + (r & 15)) * 16 + (ec & 7) * 2;
    float bE[2][4][2];
#pragma unroll
    for (int g = 0; g < 4; ++g)
#pragma unroll
        for (int e = 0; e < 2; ++e) {
            bE[0][g][e] = bias0[g * NH + ecol + e];
            bE[1][g][e] = bias1[g * NH + ecol + e];
        }

    float c0[2] = {0.f, 0.f}, c1[2] = {0.f, 0.f};
    f32x4 acc0[2], acc1[2];

    for (int p = 0; p <= NT; ++p) {
        const int pb_ = (p - 1) & 1;
        const int cb_ = p & 1;
        const int pp = (p < NT) ? p : NT - 1; // clamp x addr at p==NT (unused)
        const char* xsb = xBase + (size_t)pp * 512;

        // ---- stage one k-step t into slot t&3 ----
        auto STAGE = [&](int t) {
            if (t >= NSTEP) return;
            char* sl = ldsRaw + (t & 3) * SLOT;
            // B: every wave stages its own 2 KB (hi+lo)
            const char* bs = wpkCT + (size_t)t * 16384 + (size_t)wv * 2048 + (size_t)lane * 16;
            GLDS0(bs, sl + 4096 + wv * 2048);
            GLDS0(bs + 1024, sl + 4096 + wv * 2048 + 1024);
            // A: waves 0,2,4,6 stage one 1 KB op each
            if (!(wv & 1)) {
                const int oa = wv >> 1;
                if (t >= 16 && t < 20) { // x fp32: oa -> (rb, half)
                    const int rb = oa >> 1, h2 = oa & 1;
                    const char* xs = xsb + (size_t)rb * 8388608 + h2 * 16 + (size_t)(t - 16) * 128;
                    GLDS0(xs, sl + oa * 1024);
                } else {                 // h f16 planes: oa -> (pl, rb)
                    const int apl = oa >> 1, rb = oa & 1;
                    int kb, buf;
                    if (t < 16)      { kb = t;      buf = pb_; }
                    else if (t < 36) { kb = t - 20; buf = pb_; }
                    else             { kb = t - 36; buf = 2 + cb_; }
                    const char* hs = hbB + (size_t)buf * MBUF + (size_t)apl * PL
                                   + (size_t)(rb0 + rb) * 16384 + (size_t)kb * 1024 + (size_t)lane * 16;
                    GLDS17(hs, sl + (apl * 2 + rb) * 1024);
                }
            }
        };

        // ---- compute one k-step ----
        auto COMPUTE = [&](int s) {
            const char* sl = ldsRaw + (s & 3) * SLOT;
            f16x8 Bh = *(const f16x8*)(sl + 4096 + wv * 2048 + lane * 16);
            f16x8 Bl = *(const f16x8*)(sl + 4096 + wv * 2048 + 1024 + lane * 16);
            if (s >= 16 && s < 20) {
#pragma unroll
                for (int rf = 0; rf < 2; ++rf) {
                    f32x4 u0 = *(const f32x4*)(sl + (rf * 2) * 1024 + lane * 16);
                    f32x4 u1 = *(const f32x4*)(sl + (rf * 2 + 1) * 1024 + lane * 16);
                    f16x8 xh, xl;
                    splitr(u0, u1, xh, xl);
                    acc0[rf] = MFMA(xh, Bh, acc0[rf]);
                    acc0[rf] = MFMA(xh, Bl, acc0[rf]);
                    acc0[rf] = MFMA(xl, Bh, acc0[rf]);
                }
            } else {
                f32x4* A = (s < 20) ? acc0 : acc1;
#pragma unroll
                for (int rf = 0; rf < 2; ++rf) {
                    f16x8 ah = *(const f16x8*)(sl + rf * 1024 + lane * 16);
                    f16x8 al = *(const f16x8*)(sl + 2048 + rf * 1024 + lane * 16);
                    A[rf] = MFMA(ah, Bh, A[rf]);
                    A[rf] = MFMA(ah, Bl, A[rf]);
                    A[rf] = MFMA(al, Bh, A[rf]);
                }
            }
        };

        {
            f32x4 z = {0.f, 0.f, 0.f, 0.f};
            acc0[0] = z; acc0[1] = z; acc1[0] = z; acc1[1] = z;
        }

        // prologue: stage steps 0..2
        STAGE(0); STAGE(1); STAGE(2);

        for (int s = 0; s < 50; ++s) {
            if (!(wv & 1)) VMW(6); else VMW(4); // own step-s ops done
            BAR();                              // everyone's step-s data in LDS
            COMPUTE(s);
            if (s == 19) {
                // ---- L0 done: dump gates, fused cell L0 ----
                const int g_ = wv >> 1, ch_ = wv & 1;
#pragma unroll
                for (int rf = 0; rf < 2; ++rf)
#pragma unroll
                    for (int rg = 0; rg < 4; ++rg)
                        ldsC[(g_ * 32 + rf * 16 + kg * 4 + rg) * 34 + ch_ * 16 + lm] = acc0[rf][rg];
                __syncthreads();
                if (p < NT) {
                    float gv[4][2];
#pragma unroll
                    for (int g = 0; g < 4; ++g) {
                        float2 v = *(const float2*)&ldsC[(g * 32 + er) * 34 + ec];
                        gv[g][0] = v.x + bE[0][g][0];
                        gv[g][1] = v.y + bE[0][g][1];
                    }
                    f16 hh[2], hl[2];
#pragma unroll
                    for (int e = 0; e < 2; ++e) {
                        const float cn = sigf(gv[1][e]) * c0[e] + sigf(gv[0][e]) * tanhf(gv[2][e]);
                        c0[e] = cn;
                        const float h = sigf(gv[3][e]) * tanhf(cn);
                        hh[e] = (f16)h;
                        hl[e] = (f16)(h - (float)hh[e]);
                    }
                    char* d = hbB + (size_t)cb_ * MBUF + sbyteP;
                    cstore2(d, hh[0], hh[1]);
                    cstore2(d + PL, hl[0], hl[1]);
                }
                __syncthreads();
            }
            LGKM0();
            STAGE(s + 3);
        }
        // tail: s = 50, 51
        if (!(wv & 1)) VMW(3); else VMW(2);
        BAR();
        COMPUTE(50);
        VMW(0);
        BAR();
        COMPUTE(51);

        // ---- L1 done: dump gates, fused cell L1 ----
        {
            const int g_ = wv >> 1, ch_ = wv & 1;
#pragma unroll
            for (int rf = 0; rf < 2; ++rf)
#pragma unroll
                for (int rg = 0; rg < 4; ++rg)
                    ldsC[(g_ * 32 + rf * 16 + kg * 4 + rg) * 34 + ch_ * 16 + lm] = acc1[rf][rg];
        }
        __syncthreads();
        if (p >= 1) {
            float gv[4][2];
#pragma unroll
            for (int g = 0; g < 4; ++g) {
                float2 v = *(const float2*)&ldsC[(g * 32 + er) * 34 + ec];
                gv[g][0] = v.x + bE[1][g][0];
                gv[g][1] = v.y + bE[1][g][1];
            }
            f16 hh[2], hl[2];
            float hv[2];
#pragma unroll
            for (int e = 0; e < 2; ++e) {
                const float cn = sigf(gv[1][e]) * c1[e] + sigf(gv[0][e]) * tanhf(gv[2][e]);
                c1[e] = cn;
                const float h = sigf(gv[3][e]) * tanhf(cn);
                hv[e] = h;
                hh[e] = (f16)h;
                hl[e] = (f16)(h - (float)hh[e]);
            }
            char* d = hbB + (size_t)(2 + pb_) * MBUF + sbyteP;
            cstore2(d, hh[0], hh[1]);
            cstore2(d + PL, hl[0], hl[1]);
            if (p == NT) {
                const size_t off = (size_t)r * NH + ecol;
                h1f[off] = hv[0];
                h1f[off + 1] = hv[1];
            }
        }

        // ---- grid barrier ----
        if (p < NT) {
            __syncthreads(); // full drain: h stores visible at coherent point
            if (tid == 0) {
                __hip_atomic_fetch_add(gbar, 1u, __ATOMIC_RELAXED, __HIP_MEMORY_SCOPE_AGENT);
                const unsigned tgt = (unsigned)(p + 1) * NBLK;
                while (__hip_atomic_load(gbar, __ATOMIC_RELAXED, __HIP_MEMORY_SCOPE_AGENT) < tgt) {
                    __builtin_amdgcn_s_sleep(1);
                }
            }
            __syncthreads();
            asm volatile("" ::: "memory");
        }
    }
}

// ---------------- binarize + FC ----------------
__global__ __launch_bounds__(256) void fc_kernel(
    const float* __restrict__ h1f, const float* __restrict__ Wfc,
    const float* __restrict__ bfc, float* __restrict__ out)
{
    const int t = blockIdx.x * blockDim.x + threadIdx.x;
    const int b = t >> 5;
    const int o = t & 31;
    const float4* hr = (const float4*)(h1f + (size_t)b * NH);
    const float4* wr = (const float4*)(Wfc + (size_t)o * NH);
    float s = 0.f;
#pragma unroll 4
    for (int j = 0; j < NH / 4; ++j) {
        float4 h4 = hr[j];
        float4 w4 = wr[j];
        s += (h4.x > 0.f ? w4.x : 0.f) + (h4.y > 0.f ? w4.y : 0.f)
           + (h4.z > 0.f ? w4.z : 0.f) + (h4.w > 0.f ? w4.w : 0.f);
    }
    out[t] = s + bfc[o];
}

extern "C" void kernel_launch(void* const* d_in, const int* in_sizes, int n_in,
                              void* d_out, int out_size, void* d_ws, size_t ws_size,
                              hipStream_t stream) {
    const float* x    = (const float*)d_in[0];
    const float* Wih0 = (const float*)d_in[1];
    const float* Whh0 = (const float*)d_in[2];
    const float* bih0 = (const float*)d_in[3];
    const float* bhh0 = (const float*)d_in[4];
    const float* Wih1 = (const float*)d_in[5];
    const float* Whh1 = (const float*)d_in[6];
    const float* bih1 = (const float*)d_in[7];
    const float* bhh1 = (const float*)d_in[8];
    const float* Wfc  = (const float*)d_in[9];
    const float* bfc  = (const float*)d_in[10];
    float* out = (float*)d_out;
    (void)in_sizes; (void)n_in; (void)out_size; (void)ws_size;

    // workspace layout (~19 MB)
    char* w = (char*)d_ws;
    unsigned* sync = (unsigned*)w;                 // 8 KB sync region
    char* hb = w + 8192;                           // 4 x 1 MB h buffers (hi|lo planes)
    char* after_hb = hb + (size_t)4 * MBUF;
    float* h1f = (float*)after_hb;                 // 1 MB
    float* bias0 = (float*)(after_hb + (size_t)NB * NH * 4);
    float* bias1 = bias0 + NGC;
    f16* Wpk = (f16*)(bias1 + NGC);                // 13.6 MB packed weights

    // zero sync counters + h buffers (h(-1)=0); replayed each graph launch
    hipMemsetAsync(d_ws, 0, 8192 + (size_t)4 * MBUF, stream);

    prep_kernel<<<2048, 256, 0, stream>>>(Wih0, Whh0, bih0, bhh0, Wih1, Whh1, bih1, bhh1,
                                          Wpk, bias0, bias1);

    lstm_kernel<<<NBLK, NTHR, 0, stream>>>(x, Wpk, bias0, bias1, hb, sync, h1f);

    fc_kernel<<<64, 256, 0, stream>>>(h1f, Wfc, bfc, out);
}

// Round 10
// 32709.271 us; speedup vs baseline: 2.3819x; 1.1767x over previous
//
#include <hip/hip_runtime.h>
#include <hip/hip_bf16.h>

// LSTM (2-layer, T=1024) + STE binarize + FC, MI355X.
// Round 10 = Round 8 skeleton (passed, 38.5ms; B staged via LDS-DMA, 4x20KB
// slot ring, lookahead-3, even/odd VMW(6)/VMW(4)) + ONLY:
//  (1) fully-unrolled 52-step K-loop (compile-time addresses/branches;
//      R8's VALUBusy=27.9% was runtime addr/slot math in the lambda loop),
//  (2) cells hoisted out of the loop (no mid-loop syncthreads),
//  (3) ldsC holds both layers (LDS 116.7KB -> 1 block/CU, same placement).

typedef _Float16 f16;
typedef __attribute__((ext_vector_type(8))) _Float16 f16x8;
typedef __attribute__((ext_vector_type(4))) float f32x4;

#define MFMA(a, b, c) __builtin_amdgcn_mfma_f32_16x16x32_f16((a), (b), (c), 0, 0, 0)

#define GLDS0(g, l)  __builtin_amdgcn_global_load_lds((const __attribute__((address_space(1))) unsigned*)(g), (__attribute__((address_space(3))) unsigned*)(l), 16, 0, 0)
#define GLDS17(g, l) __builtin_amdgcn_global_load_lds((const __attribute__((address_space(1))) unsigned*)(g), (__attribute__((address_space(3))) unsigned*)(l), 16, 0, 17)
#define VMW(n) do { asm volatile("s_waitcnt vmcnt(" #n ")" ::: "memory"); __builtin_amdgcn_sched_barrier(0); } while (0)
#define BARR() do { __builtin_amdgcn_s_barrier(); __builtin_amdgcn_sched_barrier(0); } while (0)
#define LGKM0() do { asm volatile("s_waitcnt lgkmcnt(0)" ::: "memory"); __builtin_amdgcn_sched_barrier(0); } while (0)

#define NB 512
#define NT 1024
#define NH 512
#define NF 128
#define NGC 2048
#define NBLK 256
#define NTHR 512
#define MBUF 1048576  // bytes per h buffer (hi plane + lo plane)
#define PL 524288     // plane stride
#define SLOT 20480    // LDS slot: A 4KB + B 16KB
#define NSTEP 52
#define WCT 851968    // Wpk bytes per colTile (52 steps * 16384)
#define GETREG_XCC 63508

__device__ __forceinline__ float sigf(float v) { return 1.0f / (1.0f + expf(-v)); }

__device__ __forceinline__ void cstore2(void* p, f16 a, f16 b) {
    union { f16 h[2]; unsigned u; } x;
    x.h[0] = a; x.h[1] = b;
    __hip_atomic_store((unsigned*)p, x.u, __ATOMIC_RELAXED, __HIP_MEMORY_SCOPE_AGENT);
}

__device__ __forceinline__ void splitr(f32x4 u0, f32x4 u1, f16x8& hi, f16x8& lo) {
#pragma unroll
    for (int e = 0; e < 4; ++e) {
        float v = u0[e];
        f16 h = (f16)v;
        hi[e] = h;
        lo[e] = (f16)(v - (float)h);
    }
#pragma unroll
    for (int e = 0; e < 4; ++e) {
        float v = u1[e];
        f16 h = (f16)v;
        hi[4 + e] = h;
        lo[4 + e] = (f16)(v - (float)h);
    }
}

// ---------------- prep: DMA-native packed weights + biases (same as R8) ----------------
// Wpk: [ct 16][step 52][wave 8][plane 2][lane 64][elem 8] f16
// step: 0-15 Whh0, 16-19 Wih0, 20-35 Wih1, 36-51 Whh1; wave: gate=w>>1, ch=w&1
__global__ __launch_bounds__(256) void prep_kernel(
    const float* __restrict__ Wih0, const float* __restrict__ Whh0,
    const float* __restrict__ bih0, const float* __restrict__ bhh0,
    const float* __restrict__ Wih1, const float* __restrict__ Whh1,
    const float* __restrict__ bih1, const float* __restrict__ bhh1,
    f16* __restrict__ Wpk, float* __restrict__ bias0, float* __restrict__ bias1)
{
    const int stride = gridDim.x * blockDim.x;
    const int idx = blockIdx.x * blockDim.x + threadIdx.x;
    const int total = 16 * 52 * 8 * 2 * 64 * 8;
    for (int i = idx; i < total; i += stride) {
        const int e = i & 7;
        const int l = (i >> 3) & 63;
        const int pl = (i >> 9) & 1;
        const int w = (i >> 10) & 7;
        const int rest = i >> 13;
        const int s = rest % 52;
        const int ct = rest / 52;
        const int g = w >> 1, ch = w & 1;
        const int gcol = g * 512 + ct * 32 + ch * 16 + (l & 15);
        const int kk = (l >> 4) * 8 + e;
        float v;
        if (s < 16)      v = Whh0[gcol * 512 + s * 32 + kk];
        else if (s < 20) v = Wih0[gcol * 128 + (s - 16) * 32 + kk];
        else if (s < 36) v = Wih1[gcol * 512 + (s - 20) * 32 + kk];
        else             v = Whh1[gcol * 512 + (s - 36) * 32 + kk];
        const f16 hi = (f16)v;
        Wpk[i] = pl ? (f16)(v - (float)hi) : hi;
    }
    for (int i = idx; i < NGC; i += stride) {
        bias0[i] = bih0[i] + bhh0[i];
        bias1[i] = bih1[i] + bhh1[i];
    }
}

// ---------------- main persistent LSTM kernel ----------------
__global__ __launch_bounds__(NTHR, 2) void lstm_kernel(
    const float* __restrict__ x,
    const f16* __restrict__ Wpk,
    const float* __restrict__ bias0, const float* __restrict__ bias1,
    char* hbB, unsigned* sync,
    float* __restrict__ h1f)
{
    const int tid = threadIdx.x;
    const int lane = tid & 63;
    const int wv = tid >> 6;       // gate = wv>>1, colhalf = wv&1
    const int kg = lane >> 4;
    const int lm = lane & 15;
    const bool evw = (wv & 1) == 0;
    const int oa = wv >> 1;        // A-stage op index (even waves)

    __shared__ char ldsRaw[4 * SLOT] __attribute__((aligned(16))); // 81920 B slot ring
    __shared__ float ldsC[2][4][32][34];                           // 34816 B gate tiles
    __shared__ int sSlot;

    // ---- real-XCD placement: getreg + slot claim (1 block/CU via 116KB LDS) ----
    const unsigned xcd = (unsigned)__builtin_amdgcn_s_getreg(GETREG_XCC) & 7u;
    unsigned* gbar    = sync;
    unsigned* slotCtr = sync + 128 + xcd * 64;
    if (tid == 0) sSlot = (int)__hip_atomic_fetch_add(slotCtr, 1u, __ATOMIC_RELAXED, __HIP_MEMORY_SCOPE_AGENT);
    __syncthreads();
    const int slot = sSlot & 31;
    const int rowTile = slot >> 1;                 // 0..15 (32 rows)
    const int colTile = (int)xcd * 2 + (slot & 1); // 0..15 (32 h-cols)
    const int row0 = rowTile * 32;
    const int rb0 = rowTile * 2;

    const char* wpkCT = (const char*)Wpk + (size_t)colTile * WCT;
    // x per-lane base: row (row0+lm), feature kg*8; +rb*XR, +h2*16, +step*128 at stage
    const char* xBase = (const char*)x + (size_t)(row0 + lm) * 524288 + (size_t)kg * 32;
    // h per-lane base for A staging (even waves): + buf*MBUF + apl*PL + kb*1024
    const char* hABase = hbB + (size_t)(rb0 + (oa & 1)) * 16384 + (size_t)(oa >> 1) * PL + (size_t)lane * 16;

    // epilogue mapping
    const int er = tid >> 4;
    const int ec = (tid & 15) * 2;
    const int ecol = colTile * 32 + ec;
    const int r = row0 + er;
    const size_t sbyteP = (size_t)(r >> 4) * 16384 + (size_t)colTile * 1024
                        + (size_t)((ec >> 3) * 16 + (r & 15)) * 16 + (ec & 7) * 2;
    float bE[2][4][2];
#pragma unroll
    for (int g = 0; g < 4; ++g)
#pragma unroll
        for (int e = 0; e < 2; ++e) {
            bE[0][g][e] = bias0[g * NH + ecol + e];
            bE[1][g][e] = bias1[g * NH + ecol + e];
        }

    float c0[2] = {0.f, 0.f}, c1[2] = {0.f, 0.f};

    for (int p = 0; p <= NT; ++p) {
        const int pb_ = (p - 1) & 1;
        const int cb_ = p & 1;
        const int pp = (p < NT) ? p : NT - 1;
        const char* xph = xBase + (size_t)pp * 512;

        f32x4 acc0[2], acc1[2];
        {
            f32x4 z = {0.f, 0.f, 0.f, 0.f};
            acc0[0] = z; acc0[1] = z; acc1[0] = z; acc1[1] = z;
        }

        // ---- stage step t into slot t&3 (compile-time t after unroll) ----
        // B: every wave stages its own 2KB (2 GLDS). A: even waves 1 GLDS.
#define STAGE(t_) do { if ((t_) < NSTEP) {                                              \
            char* sl_ = ldsRaw + ((t_) & 3) * SLOT;                                     \
            const char* bs_ = wpkCT + (size_t)(t_) * 16384 + (size_t)wv * 2048          \
                            + (size_t)lane * 16;                                        \
            GLDS0(bs_, sl_ + 4096 + wv * 2048);                                         \
            GLDS0(bs_ + 1024, sl_ + 4096 + wv * 2048 + 1024);                           \
            if (evw) {                                                                  \
                if ((t_) >= 16 && (t_) < 20) {                                          \
                    GLDS0(xph + (size_t)(oa >> 1) * 8388608 + (oa & 1) * 16             \
                          + (size_t)((t_) - 16) * 128, sl_ + oa * 1024);                \
                } else {                                                                \
                    const int kb_ = ((t_) < 16) ? (t_)                                  \
                                  : (((t_) < 36) ? (t_) - 20 : (t_) - 36);              \
                    const int bf_ = ((t_) < 36) ? pb_ : 2 + cb_;                        \
                    GLDS17(hABase + (size_t)bf_ * MBUF + (size_t)kb_ * 1024,            \
                           sl_ + oa * 1024);                                            \
                } } } } while (0)

        // prologue: steps 0..2
        STAGE(0); STAGE(1); STAGE(2);

        // ---- fully-unrolled 52-step K-loop ----
#pragma unroll
        for (int s = 0; s < NSTEP; ++s) {
            if (evw) {
                if (s <= 49) VMW(6);
                else if (s == 50) VMW(3);
                else VMW(0);
            } else {
                if (s <= 49) VMW(4);
                else if (s == 50) VMW(2);
                else VMW(0);
            }
            BARR();
            {
                const char* sl = ldsRaw + (s & 3) * SLOT;
                f16x8 Bh = *(const f16x8*)(sl + 4096 + wv * 2048 + lane * 16);
                f16x8 Bl = *(const f16x8*)(sl + 4096 + wv * 2048 + 1024 + lane * 16);
                if (s >= 16 && s < 20) {
#pragma unroll
                    for (int rf = 0; rf < 2; ++rf) {
                        f32x4 u0 = *(const f32x4*)(sl + (rf * 2) * 1024 + lane * 16);
                        f32x4 u1 = *(const f32x4*)(sl + (rf * 2 + 1) * 1024 + lane * 16);
                        f16x8 xh, xl;
                        splitr(u0, u1, xh, xl);
                        acc0[rf] = MFMA(xh, Bh, acc0[rf]);
                        acc0[rf] = MFMA(xh, Bl, acc0[rf]);
                        acc0[rf] = MFMA(xl, Bh, acc0[rf]);
                    }
                } else if (s < 20) {
#pragma unroll
                    for (int rf = 0; rf < 2; ++rf) {
                        f16x8 ah = *(const f16x8*)(sl + rf * 1024 + lane * 16);
                        f16x8 al = *(const f16x8*)(sl + 2048 + rf * 1024 + lane * 16);
                        acc0[rf] = MFMA(ah, Bh, acc0[rf]);
                        acc0[rf] = MFMA(ah, Bl, acc0[rf]);
                        acc0[rf] = MFMA(al, Bh, acc0[rf]);
                    }
                } else {
#pragma unroll
                    for (int rf = 0; rf < 2; ++rf) {
                        f16x8 ah = *(const f16x8*)(sl + rf * 1024 + lane * 16);
                        f16x8 al = *(const f16x8*)(sl + 2048 + rf * 1024 + lane * 16);
                        acc1[rf] = MFMA(ah, Bh, acc1[rf]);
                        acc1[rf] = MFMA(ah, Bl, acc1[rf]);
                        acc1[rf] = MFMA(al, Bh, acc1[rf]);
                    }
                }
            }
            LGKM0();
            STAGE(s + 3);
        }
#undef STAGE

        // ---- dump both layers' gates, one sync, fused cells ----
        {
            const int g_ = wv >> 1, ch_ = wv & 1;
#pragma unroll
            for (int rf = 0; rf < 2; ++rf)
#pragma unroll
                for (int rg = 0; rg < 4; ++rg) {
                    ldsC[0][g_][rf * 16 + kg * 4 + rg][ch_ * 16 + lm] = acc0[rf][rg];
                    ldsC[1][g_][rf * 16 + kg * 4 + rg][ch_ * 16 + lm] = acc1[rf][rg];
                }
        }
        __syncthreads();
        if (p < NT) {
            float gv[4][2];
#pragma unroll
            for (int g = 0; g < 4; ++g) {
                float2 v = *(const float2*)&ldsC[0][g][er][ec];
                gv[g][0] = v.x + bE[0][g][0];
                gv[g][1] = v.y + bE[0][g][1];
            }
            f16 hh[2], hl[2];
#pragma unroll
            for (int e = 0; e < 2; ++e) {
                const float cn = sigf(gv[1][e]) * c0[e] + sigf(gv[0][e]) * tanhf(gv[2][e]);
                c0[e] = cn;
                const float h = sigf(gv[3][e]) * tanhf(cn);
                hh[e] = (f16)h;
                hl[e] = (f16)(h - (float)hh[e]);
            }
            char* d = hbB + (size_t)cb_ * MBUF + sbyteP;
            cstore2(d, hh[0], hh[1]);
            cstore2(d + PL, hl[0], hl[1]);
        }
        if (p >= 1) {
            float gv[4][2];
#pragma unroll
            for (int g = 0; g < 4; ++g) {
                float2 v = *(const float2*)&ldsC[1][g][er][ec];
                gv[g][0] = v.x + bE[1][g][0];
                gv[g][1] = v.y + bE[1][g][1];
            }
            f16 hh[2], hl[2];
            float hv[2];
#pragma unroll
            for (int e = 0; e < 2; ++e) {
                const float cn = sigf(gv[1][e]) * c1[e] + sigf(gv[0][e]) * tanhf(gv[2][e]);
                c1[e] = cn;
                const float h = sigf(gv[3][e]) * tanhf(cn);
                hv[e] = h;
                hh[e] = (f16)h;
                hl[e] = (f16)(h - (float)hh[e]);
            }
            char* d = hbB + (size_t)(2 + pb_) * MBUF + sbyteP;
            cstore2(d, hh[0], hh[1]);
            cstore2(d + PL, hl[0], hl[1]);
            if (p == NT) {
                const size_t off = (size_t)r * NH + ecol;
                h1f[off] = hv[0];
                h1f[off + 1] = hv[1];
            }
        }

        // ---- grid barrier ----
        if (p < NT) {
            __syncthreads(); // drains vmcnt: h stores visible at coherent point
            if (tid == 0) {
                __hip_atomic_fetch_add(gbar, 1u, __ATOMIC_RELAXED, __HIP_MEMORY_SCOPE_AGENT);
                const unsigned tgt = (unsigned)(p + 1) * NBLK;
                while (__hip_atomic_load(gbar, __ATOMIC_RELAXED, __HIP_MEMORY_SCOPE_AGENT) < tgt) {
                    __builtin_amdgcn_s_sleep(1);
                }
            }
            __syncthreads();
            asm volatile("" ::: "memory");
        }
    }
}

// ---------------- binarize + FC ----------------
__global__ __launch_bounds__(256) void fc_kernel(
    const float* __restrict__ h1f, const float* __restrict__ Wfc,
    const float* __restrict__ bfc, float* __restrict__ out)
{
    const int t = blockIdx.x * blockDim.x + threadIdx.x;
    const int b = t >> 5;
    const int o = t & 31;
    const float4* hr = (const float4*)(h1f + (size_t)b * NH);
    const float4* wr = (const float4*)(Wfc + (size_t)o * NH);
    float s = 0.f;
#pragma unroll 4
    for (int j = 0; j < NH / 4; ++j) {
        float4 h4 = hr[j];
        float4 w4 = wr[j];
        s += (h4.x > 0.f ? w4.x : 0.f) + (h4.y > 0.f ? w4.y : 0.f)
           + (h4.z > 0.f ? w4.z : 0.f) + (h4.w > 0.f ? w4.w : 0.f);
    }
    out[t] = s + bfc[o];
}

extern "C" void kernel_launch(void* const* d_in, const int* in_sizes, int n_in,
                              void* d_out, int out_size, void* d_ws, size_t ws_size,
                              hipStream_t stream) {
    const float* x    = (const float*)d_in[0];
    const float* Wih0 = (const float*)d_in[1];
    const float* Whh0 = (const float*)d_in[2];
    const float* bih0 = (const float*)d_in[3];
    const float* bhh0 = (const float*)d_in[4];
    const float* Wih1 = (const float*)d_in[5];
    const float* Whh1 = (const float*)d_in[6];
    const float* bih1 = (const float*)d_in[7];
    const float* bhh1 = (const float*)d_in[8];
    const float* Wfc  = (const float*)d_in[9];
    const float* bfc  = (const float*)d_in[10];
    float* out = (float*)d_out;
    (void)in_sizes; (void)n_in; (void)out_size; (void)ws_size;

    // workspace layout (~19 MB)
    char* w = (char*)d_ws;
    unsigned* sync = (unsigned*)w;                 // 8 KB sync region
    char* hb = w + 8192;                           // 4 x 1 MB h buffers (hi|lo planes)
    char* after_hb = hb + (size_t)4 * MBUF;
    float* h1f = (float*)after_hb;                 // 1 MB
    float* bias0 = (float*)(after_hb + (size_t)NB * NH * 4);
    float* bias1 = bias0 + NGC;
    f16* Wpk = (f16*)(bias1 + NGC);                // 13.6 MB packed weights

    // zero sync counters + h buffers (h(-1)=0); replayed each graph launch
    hipMemsetAsync(d_ws, 0, 8192 + (size_t)4 * MBUF, stream);

    prep_kernel<<<2048, 256, 0, stream>>>(Wih0, Whh0, bih0, bhh0, Wih1, Whh1, bih1, bhh1,
                                          Wpk, bias0, bias1);

    lstm_kernel<<<NBLK, NTHR, 0, stream>>>(x, Wpk, bias0, bias1, hb, sync, h1f);

    fc_kernel<<<64, 256, 0, stream>>>(h1f, Wfc, bfc, out);
}

// Round 11
// 30657.114 us; speedup vs baseline: 2.5413x; 1.0669x over previous
//
#include <hip/hip_runtime.h>
#include <hip/hip_bf16.h>

// LSTM (2-layer, T=1024) + STE binarize + FC, MI355X.
// Round 11 = Round 10 (passed, 32.7ms) + ONE change: B weights no longer
// staged through LDS (no cross-wave sharing -> pure LDS-pipe waste, and R10
// was LDS-bound at ~68KB/step). B now loads to a 3-deep register ring via
// asm global_load_dwordx4, unified vmcnt FIFO with the A LDS-DMA ring.
// Per-step LDS traffic 68KB -> 36KB.

typedef _Float16 f16;
typedef __attribute__((ext_vector_type(8))) _Float16 f16x8;
typedef __attribute__((ext_vector_type(4))) float f32x4;

#define MFMA(a, b, c) __builtin_amdgcn_mfma_f32_16x16x32_f16((a), (b), (c), 0, 0, 0)
#define H8(v) __builtin_bit_cast(f16x8, v)

#define GLDS0(g, l)  __builtin_amdgcn_global_load_lds((const __attribute__((address_space(1))) unsigned*)(g), (__attribute__((address_space(3))) unsigned*)(l), 16, 0, 0)
#define GLDS17(g, l) __builtin_amdgcn_global_load_lds((const __attribute__((address_space(1))) unsigned*)(g), (__attribute__((address_space(3))) unsigned*)(l), 16, 0, 17)
#define GLC(dst, ptr) asm volatile("global_load_dwordx4 %0, %1, off" : "=v"(dst) : "v"(ptr) : "memory")
#define VMW(n) do { asm volatile("s_waitcnt vmcnt(" #n ")" ::: "memory"); __builtin_amdgcn_sched_barrier(0); } while (0)
#define BARR() do { __builtin_amdgcn_s_barrier(); __builtin_amdgcn_sched_barrier(0); } while (0)
#define LGKM0() do { asm volatile("s_waitcnt lgkmcnt(0)" ::: "memory"); __builtin_amdgcn_sched_barrier(0); } while (0)

#define NB 512
#define NT 1024
#define NH 512
#define NF 128
#define NGC 2048
#define NBLK 256
#define NTHR 512
#define MBUF 1048576  // bytes per h buffer (hi plane + lo plane)
#define PL 524288     // plane stride
#define ASLOT 4096    // LDS A slot (4 x 1KB quarters)
#define NSTEP 52
#define WCT 851968    // Wpk bytes per colTile (52 steps * 16384)
#define GETREG_XCC 63508

__device__ __forceinline__ float sigf(float v) { return 1.0f / (1.0f + expf(-v)); }

__device__ __forceinline__ void cstore2(void* p, f16 a, f16 b) {
    union { f16 h[2]; unsigned u; } x;
    x.h[0] = a; x.h[1] = b;
    __hip_atomic_store((unsigned*)p, x.u, __ATOMIC_RELAXED, __HIP_MEMORY_SCOPE_AGENT);
}

__device__ __forceinline__ void splitr(f32x4 u0, f32x4 u1, f16x8& hi, f16x8& lo) {
#pragma unroll
    for (int e = 0; e < 4; ++e) {
        float v = u0[e];
        f16 h = (f16)v;
        hi[e] = h;
        lo[e] = (f16)(v - (float)h);
    }
#pragma unroll
    for (int e = 0; e < 4; ++e) {
        float v = u1[e];
        f16 h = (f16)v;
        hi[4 + e] = h;
        lo[4 + e] = (f16)(v - (float)h);
    }
}

// ---------------- prep: packed weights + biases (identical to R8/R10) ----------------
// Wpk: [ct 16][step 52][wave 8][plane 2][lane 64][elem 8] f16
// step: 0-15 Whh0, 16-19 Wih0, 20-35 Wih1, 36-51 Whh1; wave: gate=w>>1, ch=w&1
__global__ __launch_bounds__(256) void prep_kernel(
    const float* __restrict__ Wih0, const float* __restrict__ Whh0,
    const float* __restrict__ bih0, const float* __restrict__ bhh0,
    const float* __restrict__ Wih1, const float* __restrict__ Whh1,
    const float* __restrict__ bih1, const float* __restrict__ bhh1,
    f16* __restrict__ Wpk, float* __restrict__ bias0, float* __restrict__ bias1)
{
    const int stride = gridDim.x * blockDim.x;
    const int idx = blockIdx.x * blockDim.x + threadIdx.x;
    const int total = 16 * 52 * 8 * 2 * 64 * 8;
    for (int i = idx; i < total; i += stride) {
        const int e = i & 7;
        const int l = (i >> 3) & 63;
        const int pl = (i >> 9) & 1;
        const int w = (i >> 10) & 7;
        const int rest = i >> 13;
        const int s = rest % 52;
        const int ct = rest / 52;
        const int g = w >> 1, ch = w & 1;
        const int gcol = g * 512 + ct * 32 + ch * 16 + (l & 15);
        const int kk = (l >> 4) * 8 + e;
        float v;
        if (s < 16)      v = Whh0[gcol * 512 + s * 32 + kk];
        else if (s < 20) v = Wih0[gcol * 128 + (s - 16) * 32 + kk];
        else if (s < 36) v = Wih1[gcol * 512 + (s - 20) * 32 + kk];
        else             v = Whh1[gcol * 512 + (s - 36) * 32 + kk];
        const f16 hi = (f16)v;
        Wpk[i] = pl ? (f16)(v - (float)hi) : hi;
    }
    for (int i = idx; i < NGC; i += stride) {
        bias0[i] = bih0[i] + bhh0[i];
        bias1[i] = bih1[i] + bhh1[i];
    }
}

// ---------------- main persistent LSTM kernel ----------------
__global__ __launch_bounds__(NTHR, 2) void lstm_kernel(
    const float* __restrict__ x,
    const f16* __restrict__ Wpk,
    const float* __restrict__ bias0, const float* __restrict__ bias1,
    char* hbB, unsigned* sync,
    float* __restrict__ h1f)
{
    const int tid = threadIdx.x;
    const int lane = tid & 63;
    const int wv = tid >> 6;       // gate = wv>>1, colhalf = wv&1
    const int kg = lane >> 4;
    const int lm = lane & 15;
    const bool evw = (wv & 1) == 0;
    const int oa = wv >> 1;        // A-stage op index (even waves)

    __shared__ char ldsRaw[4 * ASLOT] __attribute__((aligned(16))); // 16 KB A ring
    __shared__ float ldsC[2][4][32][34];                            // 34816 B gate tiles
    __shared__ char ldsPad[51200];                                  // force 1 block/CU
    __shared__ int sSlot;

    // ---- real-XCD placement: getreg + slot claim (1 block/CU via ~100KB LDS) ----
    const unsigned xcd = (unsigned)__builtin_amdgcn_s_getreg(GETREG_XCC) & 7u;
    unsigned* gbar    = sync;
    unsigned* slotCtr = sync + 128 + xcd * 64;
    if (tid == 0) sSlot = (int)__hip_atomic_fetch_add(slotCtr, 1u, __ATOMIC_RELAXED, __HIP_MEMORY_SCOPE_AGENT);
    __syncthreads();
    const int slot = sSlot & 31;
    if (slot < 0) ldsPad[0] = (char)tid; // keep pad alive (never true)
    const int rowTile = slot >> 1;                 // 0..15 (32 rows)
    const int colTile = (int)xcd * 2 + (slot & 1); // 0..15 (32 h-cols)
    const int row0 = rowTile * 32;
    const int rb0 = rowTile * 2;

    // B per-lane base (this wave's 2KB/step chunk)
    const char* wpkB = (const char*)Wpk + (size_t)colTile * WCT + (size_t)wv * 2048 + (size_t)lane * 16;
    // x per-lane base: row (row0+lm), feature kg*8
    const char* xBase = (const char*)x + (size_t)(row0 + lm) * 524288 + (size_t)kg * 32;
    // h per-lane base for A staging (even waves)
    const char* hABase = hbB + (size_t)(rb0 + (oa & 1)) * 16384 + (size_t)(oa >> 1) * PL + (size_t)lane * 16;

    // epilogue mapping
    const int er = tid >> 4;
    const int ec = (tid & 15) * 2;
    const int ecol = colTile * 32 + ec;
    const int r = row0 + er;
    const size_t sbyteP = (size_t)(r >> 4) * 16384 + (size_t)colTile * 1024
                        + (size_t)((ec >> 3) * 16 + (r & 15)) * 16 + (ec & 7) * 2;
    float bE[2][4][2];
#pragma unroll
    for (int g = 0; g < 4; ++g)
#pragma unroll
        for (int e = 0; e < 2; ++e) {
            bE[0][g][e] = bias0[g * NH + ecol + e];
            bE[1][g][e] = bias1[g * NH + ecol + e];
        }

    float c0[2] = {0.f, 0.f}, c1[2] = {0.f, 0.f};

    for (int p = 0; p <= NT; ++p) {
        const int pb_ = (p - 1) & 1;
        const int cb_ = p & 1;
        const int pp = (p < NT) ? p : NT - 1;
        const char* xph = xBase + (size_t)pp * 512;

        f32x4 acc0[2], acc1[2];
        {
            f32x4 z = {0.f, 0.f, 0.f, 0.f};
            acc0[0] = z; acc0[1] = z; acc1[0] = z; acc1[1] = z;
        }
        f32x4 Bst[3][2];

        // ---- stage A for step t into slot t&3 (even waves; compile-time t) ----
#define STAGE_A(t_) do { if ((t_) < NSTEP && evw) {                                     \
            char* sl_ = ldsRaw + ((t_) & 3) * ASLOT;                                    \
            if ((t_) >= 16 && (t_) < 20) {                                              \
                GLDS0(xph + (size_t)(oa >> 1) * 8388608 + (oa & 1) * 16                 \
                      + (size_t)((t_) - 16) * 128, sl_ + oa * 1024);                    \
            } else {                                                                    \
                const int kb_ = ((t_) < 16) ? (t_)                                      \
                              : (((t_) < 36) ? (t_) - 20 : (t_) - 36);                  \
                const int bf_ = ((t_) < 36) ? pb_ : 2 + cb_;                            \
                GLDS17(hABase + (size_t)bf_ * MBUF + (size_t)kb_ * 1024,                \
                       sl_ + oa * 1024);                                                \
            } } } while (0)

        // ---- load B for step t into register ring (all waves; 2 ops) ----
#define LOAD_B(t_) do { if ((t_) < NSTEP) {                                             \
            const char* b_ = wpkB + (size_t)(t_) * 16384;                               \
            GLC(Bst[(t_) % 3][0], b_);                                                  \
            GLC(Bst[(t_) % 3][1], b_ + 1024); } } while (0)

        // prologue: FIFO [A0,B0,B0, A1,B1,B1, A2,B2,B2]
        STAGE_A(0); LOAD_B(0);
        STAGE_A(1); LOAD_B(1);
        STAGE_A(2); LOAD_B(2);

        // ---- fully-unrolled 52-step K-loop ----
        // Ledger (even): outstanding at VMW = {A(s..s+2), B(s..s+2)x2} = 9,
        //   FIFO oldest = A(s),B(s)x2 -> VMW(6); s=50: 6 outst -> VMW(3); s=51: VMW(0).
        // Ledger (odd): 6 outstanding -> VMW(4); s=50: VMW(2); s=51: VMW(0).
#pragma unroll
        for (int s = 0; s < NSTEP; ++s) {
            if (evw) {
                if (s <= 49) VMW(6);
                else if (s == 50) VMW(3);
                else VMW(0);
            } else {
                if (s <= 49) VMW(4);
                else if (s == 50) VMW(2);
                else VMW(0);
            }
            BARR();
            {
                const char* sl = ldsRaw + (s & 3) * ASLOT;
                const f16x8 Bh = H8(Bst[s % 3][0]);
                const f16x8 Bl = H8(Bst[s % 3][1]);
                if (s >= 16 && s < 20) {
#pragma unroll
                    for (int rf = 0; rf < 2; ++rf) {
                        f32x4 u0 = *(const f32x4*)(sl + (rf * 2) * 1024 + lane * 16);
                        f32x4 u1 = *(const f32x4*)(sl + (rf * 2 + 1) * 1024 + lane * 16);
                        f16x8 xh, xl;
                        splitr(u0, u1, xh, xl);
                        acc0[rf] = MFMA(xh, Bh, acc0[rf]);
                        acc0[rf] = MFMA(xh, Bl, acc0[rf]);
                        acc0[rf] = MFMA(xl, Bh, acc0[rf]);
                    }
                } else if (s < 20) {
#pragma unroll
                    for (int rf = 0; rf < 2; ++rf) {
                        f16x8 ah = *(const f16x8*)(sl + rf * 1024 + lane * 16);
                        f16x8 al = *(const f16x8*)(sl + 2048 + rf * 1024 + lane * 16);
                        acc0[rf] = MFMA(ah, Bh, acc0[rf]);
                        acc0[rf] = MFMA(ah, Bl, acc0[rf]);
                        acc0[rf] = MFMA(al, Bh, acc0[rf]);
                    }
                } else {
#pragma unroll
                    for (int rf = 0; rf < 2; ++rf) {
                        f16x8 ah = *(const f16x8*)(sl + rf * 1024 + lane * 16);
                        f16x8 al = *(const f16x8*)(sl + 2048 + rf * 1024 + lane * 16);
                        acc1[rf] = MFMA(ah, Bh, acc1[rf]);
                        acc1[rf] = MFMA(ah, Bl, acc1[rf]);
                        acc1[rf] = MFMA(al, Bh, acc1[rf]);
                    }
                }
            }
            LGKM0(); // own ds_reads of slot (s-1)&3 done before overwriting it
            STAGE_A(s + 3);
            LOAD_B(s + 3);
        }
#undef STAGE_A
#undef LOAD_B

        // ---- dump both layers' gates, one sync, fused cells ----
        {
            const int g_ = wv >> 1, ch_ = wv & 1;
#pragma unroll
            for (int rf = 0; rf < 2; ++rf)
#pragma unroll
                for (int rg = 0; rg < 4; ++rg) {
                    ldsC[0][g_][rf * 16 + kg * 4 + rg][ch_ * 16 + lm] = acc0[rf][rg];
                    ldsC[1][g_][rf * 16 + kg * 4 + rg][ch_ * 16 + lm] = acc1[rf][rg];
                }
        }
        __syncthreads();
        if (p < NT) {
            float gv[4][2];
#pragma unroll
            for (int g = 0; g < 4; ++g) {
                float2 v = *(const float2*)&ldsC[0][g][er][ec];
                gv[g][0] = v.x + bE[0][g][0];
                gv[g][1] = v.y + bE[0][g][1];
            }
            f16 hh[2], hl[2];
#pragma unroll
            for (int e = 0; e < 2; ++e) {
                const float cn = sigf(gv[1][e]) * c0[e] + sigf(gv[0][e]) * tanhf(gv[2][e]);
                c0[e] = cn;
                const float h = sigf(gv[3][e]) * tanhf(cn);
                hh[e] = (f16)h;
                hl[e] = (f16)(h - (float)hh[e]);
            }
            char* d = hbB + (size_t)cb_ * MBUF + sbyteP;
            cstore2(d, hh[0], hh[1]);
            cstore2(d + PL, hl[0], hl[1]);
        }
        if (p >= 1) {
            float gv[4][2];
#pragma unroll
            for (int g = 0; g < 4; ++g) {
                float2 v = *(const float2*)&ldsC[1][g][er][ec];
                gv[g][0] = v.x + bE[1][g][0];
                gv[g][1] = v.y + bE[1][g][1];
            }
            f16 hh[2], hl[2];
            float hv[2];
#pragma unroll
            for (int e = 0; e < 2; ++e) {
                const float cn = sigf(gv[1][e]) * c1[e] + sigf(gv[0][e]) * tanhf(gv[2][e]);
                c1[e] = cn;
                const float h = sigf(gv[3][e]) * tanhf(cn);
                hv[e] = h;
                hh[e] = (f16)h;
                hl[e] = (f16)(h - (float)hh[e]);
            }
            char* d = hbB + (size_t)(2 + pb_) * MBUF + sbyteP;
            cstore2(d, hh[0], hh[1]);
            cstore2(d + PL, hl[0], hl[1]);
            if (p == NT) {
                const size_t off = (size_t)r * NH + ecol;
                h1f[off] = hv[0];
                h1f[off + 1] = hv[1];
            }
        }

        // ---- grid barrier ----
        if (p < NT) {
            __syncthreads(); // drains vmcnt: h stores visible at coherent point
            if (tid == 0) {
                __hip_atomic_fetch_add(gbar, 1u, __ATOMIC_RELAXED, __HIP_MEMORY_SCOPE_AGENT);
                const unsigned tgt = (unsigned)(p + 1) * NBLK;
                while (__hip_atomic_load(gbar, __ATOMIC_RELAXED, __HIP_MEMORY_SCOPE_AGENT) < tgt) {
                    __builtin_amdgcn_s_sleep(1);
                }
            }
            __syncthreads();
            asm volatile("" ::: "memory");
        }
    }
}

// ---------------- binarize + FC ----------------
__global__ __launch_bounds__(256) void fc_kernel(
    const float* __restrict__ h1f, const float* __restrict__ Wfc,
    const float* __restrict__ bfc, float* __restrict__ out)
{
    const int t = blockIdx.x * blockDim.x + threadIdx.x;
    const int b = t >> 5;
    const int o = t & 31;
    const float4* hr = (const float4*)(h1f + (size_t)b * NH);
    const float4* wr = (const float4*)(Wfc + (size_t)o * NH);
    float s = 0.f;
#pragma unroll 4
    for (int j = 0; j < NH / 4; ++j) {
        float4 h4 = hr[j];
        float4 w4 = wr[j];
        s += (h4.x > 0.f ? w4.x : 0.f) + (h4.y > 0.f ? w4.y : 0.f)
           + (h4.z > 0.f ? w4.z : 0.f) + (h4.w > 0.f ? w4.w : 0.f);
    }
    out[t] = s + bfc[o];
}

extern "C" void kernel_launch(void* const* d_in, const int* in_sizes, int n_in,
                              void* d_out, int out_size, void* d_ws, size_t ws_size,
                              hipStream_t stream) {
    const float* x    = (const float*)d_in[0];
    const float* Wih0 = (const float*)d_in[1];
    const float* Whh0 = (const float*)d_in[2];
    const float* bih0 = (const float*)d_in[3];
    const float* bhh0 = (const float*)d_in[4];
    const float* Wih1 = (const float*)d_in[5];
    const float* Whh1 = (const float*)d_in[6];
    const float* bih1 = (const float*)d_in[7];
    const float* bhh1 = (const float*)d_in[8];
    const float* Wfc  = (const float*)d_in[9];
    const float* bfc  = (const float*)d_in[10];
    float* out = (float*)d_out;
    (void)in_sizes; (void)n_in; (void)out_size; (void)ws_size;

    // workspace layout (~19 MB)
    char* w = (char*)d_ws;
    unsigned* sync = (unsigned*)w;                 // 8 KB sync region
    char* hb = w + 8192;                           // 4 x 1 MB h buffers (hi|lo planes)
    char* after_hb = hb + (size_t)4 * MBUF;
    float* h1f = (float*)after_hb;                 // 1 MB
    float* bias0 = (float*)(after_hb + (size_t)NB * NH * 4);
    float* bias1 = bias0 + NGC;
    f16* Wpk = (f16*)(bias1 + NGC);                // 13.6 MB packed weights

    // zero sync counters + h buffers (h(-1)=0); replayed each graph launch
    hipMemsetAsync(d_ws, 0, 8192 + (size_t)4 * MBUF, stream);

    prep_kernel<<<2048, 256, 0, stream>>>(Wih0, Whh0, bih0, bhh0, Wih1, Whh1, bih1, bhh1,
                                          Wpk, bias0, bias1);

    lstm_kernel<<<NBLK, NTHR, 0, stream>>>(x, Wpk, bias0, bias1, hb, sync, h1f);

    fc_kernel<<<64, 256, 0, stream>>>(h1f, Wfc, bfc, out);
}